// Round 5
// baseline (1487.192 us; speedup 1.0000x reference)
//
#include <hip/hip_runtime.h>
#include <hip/hip_bf16.h>
#include <math.h>

// Problem constants
#define BB 16
#define TT 12
#define NN 2048
#define FIN 32
#define FOUT 64
#define KCH 3

typedef __attribute__((ext_vector_type(8))) short vbf16x8;
typedef __attribute__((ext_vector_type(4))) float vf32x4;

// ---- dual-mode loads: mf=0 -> data is bf16, mf=1 -> data is fp32 ----------
__device__ __forceinline__ float ldf(const void* p, size_t i, int mf) {
    if (mf) return ((const float*)p)[i];
    return __bfloat162float(((const __hip_bfloat16*)p)[i]);
}

__device__ __forceinline__ void load8d(const void* p, size_t i, int mf, float* o) {
    if (mf) {
        const float* fp = (const float*)p + i;
        float4 a = *(const float4*)fp;
        float4 b = *(const float4*)(fp + 4);
        o[0] = a.x; o[1] = a.y; o[2] = a.z; o[3] = a.w;
        o[4] = b.x; o[5] = b.y; o[6] = b.z; o[7] = b.w;
    } else {
        uint4 u = *(const uint4*)((const __hip_bfloat16*)p + i);
        const __hip_bfloat16* h = (const __hip_bfloat16*)&u;
#pragma unroll
        for (int j = 0; j < 8; ++j) o[j] = __bfloat162float(h[j]);
    }
}

__device__ __forceinline__ vbf16x8 pack8(const float* v) {
    union { vbf16x8 f; __hip_bfloat16 h[8]; } u;
#pragma unroll
    for (int j = 0; j < 8; ++j) u.h[j] = __float2bfloat16(v[j]);
    return u.f;
}

// elementwise bf16 product of two uint4-packed 8-vectors -> MFMA A-frag
__device__ __forceinline__ vbf16x8 mulpack8(uint4 c, uint4 s) {
    const __hip_bfloat16* ch = (const __hip_bfloat16*)&c;
    const __hip_bfloat16* sh = (const __hip_bfloat16*)&s;
    union { vbf16x8 f; __hip_bfloat16 h[8]; } u;
#pragma unroll
    for (int j = 0; j < 8; ++j)
        u.h[j] = __float2bfloat16(__bfloat162float(ch[j]) * __bfloat162float(sh[j]));
    return u.f;
}

// ---------------------------------------------------------------------------
// Detect input dtype (bf16 vs fp32 read as halfwords). flag: 0=bf16, 1=fp32.
// ---------------------------------------------------------------------------
__global__ __launch_bounds__(256) void k_detect(const void* __restrict__ x, int* __restrict__ flag) {
    __shared__ int cnt[256];
    const unsigned short* h = (const unsigned short*)x;
    int bad = 0;
    for (int i = threadIdx.x; i < 4096; i += 256) {
        int e = (h[i] >> 7) & 0xFF;
        if (e < 110 || e > 133) bad++;
    }
    cnt[threadIdx.x] = bad;
    __syncthreads();
    for (int s = 128; s > 0; s >>= 1) {
        if ((int)threadIdx.x < s) cnt[threadIdx.x] += cnt[threadIdx.x + s];
        __syncthreads();
    }
    if (threadIdx.x == 0) flag[0] = (cnt[0] > 614) ? 1 : 0;  // >15% bad => fp32
}

// Emergency: workspace too small — loud sentinel.
__global__ __launch_bounds__(256) void k_emergency(__hip_bfloat16* out, size_t n) {
    size_t i = (size_t)blockIdx.x * 256 + threadIdx.x;
    if (i < n) out[i] = __float2bfloat16(55555.f);
}

// ---------------------------------------------------------------------------
// Convert cheb (fp32 or bf16) -> bf16 contiguous. 8 elems/thread.
// ---------------------------------------------------------------------------
__global__ __launch_bounds__(256) void k_cvt_cheb(
    const void* __restrict__ cheb, const int* __restrict__ flag,
    __hip_bfloat16* __restrict__ chebBF) {
    int mf = flag[0];
    size_t i = ((size_t)blockIdx.x * 256 + threadIdx.x) * 8;
    float v[8];
    load8d(cheb, i, mf, v);
    union { uint4 u; __hip_bfloat16 h[8]; } pv;
#pragma unroll
    for (int j = 0; j < 8; ++j) pv.h[j] = __float2bfloat16(v[j]);
    *reinterpret_cast<uint4*>(&chebBF[i]) = pv.u;
}

// ---------------------------------------------------------------------------
// Prep: Theta^T (64 x 96), Wcat^T (64 x 224), biasC (64)
// ---------------------------------------------------------------------------
__global__ __launch_bounds__(256) void k_prep(
    const void* __restrict__ theta, const void* __restrict__ tconv_w,
    const void* __restrict__ tconv_b, const void* __restrict__ rconv_w,
    const void* __restrict__ rconv_b, const int* __restrict__ flag,
    __hip_bfloat16* __restrict__ Tt, __hip_bfloat16* __restrict__ Wt, float* __restrict__ biasC) {
    int mf = flag[0];
    int tid = blockIdx.x * 256 + threadIdx.x;
    if (tid < 64 * 96) {  // Tt[o][kf] = theta[kf*64 + o]
        int o = tid / 96, kf = tid % 96;
        Tt[tid] = __float2bfloat16(ldf(theta, (size_t)kf * 64 + o, mf));
    }
    if (tid < 64 * 224) {  // Wt[o][c]
        int o = tid / 224, c = tid % 224;
        float v;
        if (c < 192) {
            int dt = c / 64, i = c % 64;
            v = ldf(tconv_w, ((size_t)o * 64 + i) * 3 + dt, mf);
        } else {
            v = ldf(rconv_w, (size_t)o * 32 + (c - 192), mf);
        }
        Wt[tid] = __float2bfloat16(v);
    }
    if (tid < 64) biasC[tid] = ldf(tconv_b, tid, mf) + ldf(rconv_b, tid, mf);
}

// ---------------------------------------------------------------------------
// K1: qt/kt  (B,T,N) fp32
// ---------------------------------------------------------------------------
__global__ __launch_bounds__(256) void k_qtkt(
    const void* __restrict__ x, const void* __restrict__ wq,
    const void* __restrict__ wk, const int* __restrict__ flag,
    float* __restrict__ qt, float* __restrict__ kt) {
    int mf = flag[0];
    __shared__ float swq[32], swk[32];
    if (threadIdx.x < 32) swq[threadIdx.x] = ldf(wq, threadIdx.x, mf);
    else if (threadIdx.x < 64) swk[threadIdx.x - 32] = ldf(wk, threadIdx.x - 32, mf);
    __syncthreads();
    size_t idx = (size_t)blockIdx.x * 256 + threadIdx.x;  // (b*T+t)*N+n
    float q = 0.f, k = 0.f;
#pragma unroll
    for (int c = 0; c < 4; ++c) {
        float v[8];
        load8d(x, idx * FIN + c * 8, mf, v);
#pragma unroll
        for (int j = 0; j < 8; ++j) { q += v[j] * swq[c * 8 + j]; k += v[j] * swk[c * 8 + j]; }
    }
    qt[idx] = q;
    kt[idx] = k;
}

// ---------------------------------------------------------------------------
// K2: temporal scores + softmax -> ta (B,T,T) fp32. One block per (b,t).
// ---------------------------------------------------------------------------
__global__ __launch_bounds__(256) void k_tattn(
    const float* __restrict__ qt, const float* __restrict__ kt, float* __restrict__ ta) {
    int b = blockIdx.x / TT, t = blockIdx.x % TT;
    const float* q = qt + ((size_t)b * TT + t) * NN;
    float part[TT];
#pragma unroll
    for (int s = 0; s < TT; ++s) part[s] = 0.f;
    for (int n = threadIdx.x; n < NN; n += 256) {
        float qv = q[n];
#pragma unroll
        for (int s = 0; s < TT; ++s) part[s] += qv * kt[((size_t)b * TT + s) * NN + n];
    }
    __shared__ float red[TT][4];
    __shared__ float sc[TT];
    int lane = threadIdx.x & 63, wid = threadIdx.x >> 6;
#pragma unroll
    for (int s = 0; s < TT; ++s) {
        float v = part[s];
#pragma unroll
        for (int m = 32; m >= 1; m >>= 1) v += __shfl_xor(v, m);
        if (lane == 0) red[s][wid] = v;
    }
    __syncthreads();
    if (threadIdx.x < TT)
        sc[threadIdx.x] = (red[threadIdx.x][0] + red[threadIdx.x][1] + red[threadIdx.x][2] +
                           red[threadIdx.x][3]) * 0.02209708691207961f;  // 1/sqrt(2048)
    __syncthreads();
    if (threadIdx.x == 0) {
        float m = sc[0];
#pragma unroll
        for (int s = 1; s < TT; ++s) m = fmaxf(m, sc[s]);
        float e[TT], sum = 0.f;
#pragma unroll
        for (int s = 0; s < TT; ++s) { e[s] = __expf(sc[s] - m); sum += e[s]; }
        float inv = 1.f / sum;
#pragma unroll
        for (int s = 0; s < TT; ++s) ta[((size_t)b * TT + t) * TT + s] = e[s] * inv;
    }
}

// ---------------------------------------------------------------------------
// K3 (per chunk): x_ta -> xT_c[bl][t*32+f][n] (bf16); qs/ks (global b) fused.
// ---------------------------------------------------------------------------
__global__ __launch_bounds__(256) void k_xta(
    const void* __restrict__ x, const float* __restrict__ ta,
    const void* __restrict__ wqs, const void* __restrict__ wks, const int* __restrict__ flag,
    __hip_bfloat16* __restrict__ xT, float* __restrict__ qs, float* __restrict__ ks, int b0) {
    int mf = flag[0];
    int gid = blockIdx.x * 256 + threadIdx.x;
    int fg = gid & 3;
    int n = (gid >> 2) & (NN - 1);
    int bl = gid >> 13;          // 0..chk-1 (block-uniform)
    int b = b0 + bl;
    __shared__ float sta[TT * TT];
    __shared__ float swq[32], swk[32];
    if (threadIdx.x < 144) sta[threadIdx.x] = ta[(size_t)b * 144 + threadIdx.x];
    else if (threadIdx.x >= 160 && threadIdx.x < 192) swq[threadIdx.x - 160] = ldf(wqs, threadIdx.x - 160, mf);
    else if (threadIdx.x >= 192 && threadIdx.x < 224) swk[threadIdx.x - 192] = ldf(wks, threadIdx.x - 192, mf);
    __syncthreads();

    float acc[TT][8];
#pragma unroll
    for (int t = 0; t < TT; ++t)
#pragma unroll
        for (int j = 0; j < 8; ++j) acc[t][j] = 0.f;

    for (int s = 0; s < TT; ++s) {
        float xv[8];
        load8d(x, (((size_t)(b * TT + s) * NN) + n) * FIN + fg * 8, mf, xv);
#pragma unroll
        for (int t = 0; t < TT; ++t) {
            float w = sta[t * TT + s];
#pragma unroll
            for (int j = 0; j < 8; ++j) acc[t][j] += w * xv[j];
        }
    }
    size_t xbase = (size_t)bl * 384 * NN;
#pragma unroll
    for (int t = 0; t < TT; ++t)
#pragma unroll
        for (int j = 0; j < 8; ++j)
            xT[xbase + (size_t)(t * 32 + fg * 8 + j) * NN + n] = __float2bfloat16(acc[t][j]);
#pragma unroll
    for (int t = 0; t < TT; ++t) {
        float pq = 0.f, pk = 0.f;
#pragma unroll
        for (int j = 0; j < 8; ++j) {
            pq += acc[t][j] * swq[fg * 8 + j];
            pk += acc[t][j] * swk[fg * 8 + j];
        }
        pq += __shfl_xor(pq, 1); pq += __shfl_xor(pq, 2);
        pk += __shfl_xor(pk, 1); pk += __shfl_xor(pk, 2);
        if (fg == 0) {
            qs[((size_t)b * NN + n) * TT + t] = pq;
            ks[((size_t)b * NN + n) * TT + t] = pk;
        }
    }
}

// ---------------------------------------------------------------------------
// K5 (per chunk): sa_c[bl][i][j] (bf16), softmax over j. 8 i-rows / block.
// ---------------------------------------------------------------------------
__global__ __launch_bounds__(256) void k_sattn(
    const float* __restrict__ qs, const float* __restrict__ ks,
    __hip_bfloat16* __restrict__ sa, int b0) {
    int bl = blockIdx.x >> 8;
    int b = b0 + bl;
    int i0 = (blockIdx.x & 255) * 8;
    __shared__ float qrow[8][TT];
    __shared__ float rbuf[4];
    if (threadIdx.x < 96) qrow[threadIdx.x / TT][threadIdx.x % TT] =
        qs[((size_t)b * NN + i0) * TT + threadIdx.x];
    __syncthreads();
    const float scale = 0.28867513459481287f;  // 1/sqrt(12)
    float sc[8][8];
#pragma unroll
    for (int c = 0; c < 8; ++c) {
        int j = threadIdx.x + (c << 8);
        const float* kr = ks + ((size_t)b * NN + j) * TT;
        float kv[TT];
        *(float4*)&kv[0] = *(const float4*)&kr[0];
        *(float4*)&kv[4] = *(const float4*)&kr[4];
        *(float4*)&kv[8] = *(const float4*)&kr[8];
#pragma unroll
        for (int r = 0; r < 8; ++r) {
            float d = 0.f;
#pragma unroll
            for (int t = 0; t < TT; ++t) d += qrow[r][t] * kv[t];
            sc[r][c] = d * scale;
        }
    }
    int lane = threadIdx.x & 63, wid = threadIdx.x >> 6;
#pragma unroll
    for (int r = 0; r < 8; ++r) {
        float v = -1e30f;
#pragma unroll
        for (int c = 0; c < 8; ++c) v = fmaxf(v, sc[r][c]);
#pragma unroll
        for (int m = 32; m >= 1; m >>= 1) v = fmaxf(v, __shfl_xor(v, m));
        if (lane == 0) rbuf[wid] = v;
        __syncthreads();
        float bmax = fmaxf(fmaxf(rbuf[0], rbuf[1]), fmaxf(rbuf[2], rbuf[3]));
        __syncthreads();
        float lsum = 0.f;
#pragma unroll
        for (int c = 0; c < 8; ++c) { float e = __expf(sc[r][c] - bmax); sc[r][c] = e; lsum += e; }
        v = lsum;
#pragma unroll
        for (int m = 32; m >= 1; m >>= 1) v += __shfl_xor(v, m);
        if (lane == 0) rbuf[wid] = v;
        __syncthreads();
        float inv = 1.f / (rbuf[0] + rbuf[1] + rbuf[2] + rbuf[3]);
        __syncthreads();
        size_t base = ((size_t)bl * NN + i0 + r) * NN + threadIdx.x;
#pragma unroll
        for (int c = 0; c < 8; ++c) sa[base + (c << 8)] = __float2bfloat16(sc[r][c] * inv);
    }
}

// ---------------------------------------------------------------------------
// K6 (per chunk): per (bl,kk):  C = (chebBF_k .* sa_bl) @ X_bl -> rhs_c
//   M=2048(i), N=384(all tf), K=2048(j).
//   r5: BARRIER-FREE. r2-r4 profiles showed MfmaUtil ~19% at occupancy
//   32-44% -> the per-step stage->barrier->ds_read chain was the critical
//   path, not bandwidth (r1 falsified) nor occupancy (r4 falsified).
//   Now the A-frag (cheb .* sa) is computed DIRECTLY in registers: each
//   lane's 8 A-elements are contiguous in cheb/sa (row mi*16+lr, k kq..kq+8)
//   -> uint4 load each, mul, pack. No LDS, no __syncthreads in the kernel.
//   Intra-block duplication (4 waves x same 32-row A slice) hits L1.
//   2-step register ping-pong prefetch keeps loads one step ahead of MFMA.
//   Block = 4 waves x (32 rows x 96 cols) = 32x384; 64 i-tiles.
// ---------------------------------------------------------------------------
__global__ __launch_bounds__(256, 2) void k_gemm_cheb(
    const __hip_bfloat16* __restrict__ chebBF, const __hip_bfloat16* __restrict__ sa,
    const __hip_bfloat16* __restrict__ xT, __hip_bfloat16* __restrict__ rhs) {
    int it = blockIdx.x;        // i tile 0..63 (32 rows each)
    int bz = blockIdx.y;        // 0..3*chk-1
    int bl = bz / 3, kk = bz % 3;

    int tid = threadIdx.x;
    int wid = tid >> 6, lane = tid & 63;
    int wn = wid * 96;            // 4 waves x 96 cols = 384
    int lr = lane & 15, kq = (lane >> 4) * 8;

    const size_t i0 = (size_t)it * 32;
    const __hip_bfloat16* cA = chebBF + (size_t)kk * NN * NN + (i0 + lr) * NN + kq;
    const __hip_bfloat16* sA = sa + (size_t)bl * NN * NN + (i0 + lr) * NN + kq;
    const __hip_bfloat16* bp = xT + (size_t)bl * 384 * NN + (size_t)(wn + lr) * NN + kq;

    vf32x4 acc[2][6];
    vf32x4 z4 = {0.f, 0.f, 0.f, 0.f};
#pragma unroll
    for (int mi = 0; mi < 2; ++mi)
#pragma unroll
        for (int ni = 0; ni < 6; ++ni) acc[mi][ni] = z4;

    uint4 cu0[2], su0[2], cu1[2], su1[2];
    vbf16x8 b0[6], b1[6];

#define K6_LOAD(CU, SU, BV, J)                                                      \
    {                                                                               \
        size_t jo = (size_t)(J) * 32;                                               \
        CU[0] = *reinterpret_cast<const uint4*>(cA + jo);                           \
        CU[1] = *reinterpret_cast<const uint4*>(cA + (size_t)16 * NN + jo);         \
        SU[0] = *reinterpret_cast<const uint4*>(sA + jo);                           \
        SU[1] = *reinterpret_cast<const uint4*>(sA + (size_t)16 * NN + jo);         \
        _Pragma("unroll")                                                           \
        for (int ni = 0; ni < 6; ++ni)                                              \
            BV[ni] = *reinterpret_cast<const vbf16x8*>(bp + (size_t)(ni * 16) * NN + jo); \
    }

#define K6_COMP(CU, SU, BV)                                                         \
    {                                                                               \
        vbf16x8 afr[2];                                                             \
        _Pragma("unroll")                                                           \
        for (int mi = 0; mi < 2; ++mi) afr[mi] = mulpack8(CU[mi], SU[mi]);          \
        _Pragma("unroll")                                                           \
        for (int ni = 0; ni < 6; ++ni)                                              \
            _Pragma("unroll")                                                       \
            for (int mi = 0; mi < 2; ++mi)                                          \
                acc[mi][ni] = __builtin_amdgcn_mfma_f32_16x16x32_bf16(              \
                    afr[mi], BV[ni], acc[mi][ni], 0, 0, 0);                         \
    }

    K6_LOAD(cu0, su0, b0, 0);
    for (int step = 0; step < 64; step += 2) {
        K6_LOAD(cu1, su1, b1, step + 1);          // step+1 <= 63
        K6_COMP(cu0, su0, b0);
        int j2 = (step + 2 < 64) ? step + 2 : 63; // tail clamp (redundant load)
        K6_LOAD(cu0, su0, b0, j2);
        K6_COMP(cu1, su1, b1);
    }
#undef K6_LOAD
#undef K6_COMP

    // epilogue: row = mi*16 + quad*4 + g; col = wn + ni*16 + lr
#pragma unroll
    for (int mi = 0; mi < 2; ++mi)
#pragma unroll
        for (int ni = 0; ni < 6; ++ni)
#pragma unroll
            for (int g = 0; g < 4; ++g) {
                int row = mi * 16 + ((lane >> 4) << 2) + g;
                int col = wn + ni * 16 + lr;
                size_t i = i0 + row;
                int t = col >> 5, f = col & 31;
                rhs[(((size_t)bl * NN + i) * TT + t) * 96 + kk * 32 + f] =
                    __float2bfloat16(acc[mi][ni][g]);
            }
}

// ---------------------------------------------------------------------------
// K7a (per chunk): G = relu(rhs @ Theta)  rows (bl,n,t), K=96, N=64
//      G stored [bl][t][n][o] bf16
// ---------------------------------------------------------------------------
__global__ __launch_bounds__(256) void k_theta(
    const __hip_bfloat16* __restrict__ rhs, const __hip_bfloat16* __restrict__ Tt,
    __hip_bfloat16* __restrict__ G) {
    __shared__ __hip_bfloat16 Ts[64][104];
    int tid = threadIdx.x;
    int srow = tid >> 2, scol = (tid & 3) * 8;
#pragma unroll
    for (int c0 = 0; c0 < 96; c0 += 32)
        *reinterpret_cast<uint4*>(&Ts[srow][c0 + scol]) =
            *reinterpret_cast<const uint4*>(&Tt[(size_t)srow * 96 + c0 + scol]);
    __syncthreads();
    int wid = tid >> 6, lane = tid & 63;
    int lr = lane & 15, kq = (lane >> 4) * 8;
    size_t r0 = (size_t)blockIdx.x * 128 + wid * 32;
    vf32x4 acc[2][4];
    vf32x4 z4 = {0.f, 0.f, 0.f, 0.f};
#pragma unroll
    for (int mi = 0; mi < 2; ++mi)
#pragma unroll
        for (int ni = 0; ni < 4; ++ni) acc[mi][ni] = z4;
#pragma unroll
    for (int s = 0; s < 3; ++s) {
        vbf16x8 a[2], bf[4];
#pragma unroll
        for (int mi = 0; mi < 2; ++mi)
            a[mi] = *reinterpret_cast<const vbf16x8*>(&rhs[(r0 + mi * 16 + lr) * 96 + s * 32 + kq]);
#pragma unroll
        for (int ni = 0; ni < 4; ++ni)
            bf[ni] = *reinterpret_cast<const vbf16x8*>(&Ts[ni * 16 + lr][s * 32 + kq]);
#pragma unroll
        for (int mi = 0; mi < 2; ++mi)
#pragma unroll
            for (int ni = 0; ni < 4; ++ni)
                acc[mi][ni] = __builtin_amdgcn_mfma_f32_16x16x32_bf16(a[mi], bf[ni], acc[mi][ni], 0, 0, 0);
    }
#pragma unroll
    for (int mi = 0; mi < 2; ++mi)
#pragma unroll
        for (int ni = 0; ni < 4; ++ni)
#pragma unroll
            for (int g = 0; g < 4; ++g) {
                size_t r = r0 + mi * 16 + ((lane >> 4) << 2) + g;  // (bl*N+n)*T+t
                int col = ni * 16 + (lane & 15);
                int t = (int)(r % TT);
                size_t bn = r / TT;
                int n = (int)(bn & (NN - 1));
                int bl = (int)(bn >> 11);
                float v = fmaxf(acc[mi][ni][g], 0.f);
                G[(((size_t)bl * TT + t) * NN + n) * 64 + col] = __float2bfloat16(v);
            }
}

// ---------------------------------------------------------------------------
// K7b (per chunk): y = relu([G(t-1),G(t),G(t+1),x] @ Wcat + bias); LayerNorm
//      block = (nblk, t, bl); 128 rows (n), K=224, N=64
// ---------------------------------------------------------------------------
__global__ __launch_bounds__(256) void k_final(
    const __hip_bfloat16* __restrict__ G, const void* __restrict__ x,
    const __hip_bfloat16* __restrict__ Wt, const float* __restrict__ biasC,
    const void* __restrict__ ln_g, const void* __restrict__ ln_b,
    const int* __restrict__ flag, void* __restrict__ outv, int b0) {
    int mf = flag[0];
    int n0 = blockIdx.x * 128;
    int t = blockIdx.y;
    int bl = blockIdx.z;
    int b = b0 + bl;
    __shared__ __hip_bfloat16 Ws[64][232];
    __shared__ float sg[64], sb[64], sbias[64];
    int tid = threadIdx.x;
    int srow = tid >> 2, scol = (tid & 3) * 8;
#pragma unroll
    for (int c0 = 0; c0 < 224; c0 += 32)
        *reinterpret_cast<uint4*>(&Ws[srow][c0 + scol]) =
            *reinterpret_cast<const uint4*>(&Wt[(size_t)srow * 224 + c0 + scol]);
    if (tid < 64) {
        sg[tid] = ldf(ln_g, tid, mf);
        sb[tid] = ldf(ln_b, tid, mf);
        sbias[tid] = biasC[tid];
    }
    __syncthreads();
    int wid = tid >> 6, lane = tid & 63;
    int lr = lane & 15, kq = (lane >> 4) * 8;
    int rw = n0 + wid * 32;
    vf32x4 acc[2][4];
    vf32x4 z4 = {0.f, 0.f, 0.f, 0.f};
#pragma unroll
    for (int mi = 0; mi < 2; ++mi)
#pragma unroll
        for (int ni = 0; ni < 4; ++ni) acc[mi][ni] = z4;

    vbf16x8 zfrag = {0, 0, 0, 0, 0, 0, 0, 0};
#pragma unroll
    for (int s = 0; s < 7; ++s) {
        int kb = s * 32;
        vbf16x8 a[2], bf[4];
#pragma unroll
        for (int ni = 0; ni < 4; ++ni)
            bf[ni] = *reinterpret_cast<const vbf16x8*>(&Ws[ni * 16 + lr][kb + kq]);
        if (s < 6) {
            int dt = s >> 1;
            int t2 = t + dt - 1;
            int off = (s & 1) * 32 + kq;
            if (t2 >= 0 && t2 < TT) {
#pragma unroll
                for (int mi = 0; mi < 2; ++mi)
                    a[mi] = *reinterpret_cast<const vbf16x8*>(
                        &G[(((size_t)bl * TT + t2) * NN + rw + mi * 16 + lr) * 64 + off]);
            } else {
                a[0] = zfrag; a[1] = zfrag;
            }
        } else {
#pragma unroll
            for (int mi = 0; mi < 2; ++mi) {
                float xv[8];
                load8d(x, (((size_t)b * TT + t) * NN + rw + mi * 16 + lr) * FIN + kq, mf, xv);
                a[mi] = pack8(xv);
            }
        }
#pragma unroll
        for (int mi = 0; mi < 2; ++mi)
#pragma unroll
            for (int ni = 0; ni < 4; ++ni)
                acc[mi][ni] = __builtin_amdgcn_mfma_f32_16x16x32_bf16(a[mi], bf[ni], acc[mi][ni], 0, 0, 0);
    }
    float vals[2][4][4];
#pragma unroll
    for (int mi = 0; mi < 2; ++mi)
#pragma unroll
        for (int ni = 0; ni < 4; ++ni) {
            int col = ni * 16 + lr;
#pragma unroll
            for (int g = 0; g < 4; ++g)
                vals[mi][ni][g] = fmaxf(acc[mi][ni][g] + sbias[col], 0.f);
        }
#pragma unroll
    for (int mi = 0; mi < 2; ++mi)
#pragma unroll
        for (int g = 0; g < 4; ++g) {
            float s1 = 0.f, s2 = 0.f;
#pragma unroll
            for (int ni = 0; ni < 4; ++ni) { float v = vals[mi][ni][g]; s1 += v; s2 += v * v; }
            s1 += __shfl_xor(s1, 1); s2 += __shfl_xor(s2, 1);
            s1 += __shfl_xor(s1, 2); s2 += __shfl_xor(s2, 2);
            s1 += __shfl_xor(s1, 4); s2 += __shfl_xor(s2, 4);
            s1 += __shfl_xor(s1, 8); s2 += __shfl_xor(s2, 8);
            float mean = s1 * (1.f / 64.f);
            float var = fmaxf(s2 * (1.f / 64.f) - mean * mean, 0.f);
            float rstd = rsqrtf(var + 1e-5f);
            int row = wid * 32 + mi * 16 + ((lane >> 4) << 2) + g;
#pragma unroll
            for (int ni = 0; ni < 4; ++ni) {
                int col = ni * 16 + lr;
                float y = (vals[mi][ni][g] - mean) * rstd * sg[col] + sb[col];
                size_t oi = (((size_t)b * TT + t) * NN + n0 + row) * 64 + col;
                if (mf) ((float*)outv)[oi] = y;
                else ((__hip_bfloat16*)outv)[oi] = __float2bfloat16(y);
            }
        }
}

// ---------------------------------------------------------------------------
extern "C" void kernel_launch(void* const* d_in, const int* in_sizes, int n_in,
                              void* d_out, int out_size, void* d_ws, size_t ws_size,
                              hipStream_t stream) {
    const void* x      = d_in[0];
    const void* cheb   = d_in[1];
    const void* wq_t   = d_in[2];
    const void* wk_t   = d_in[3];
    const void* wq_s   = d_in[4];
    const void* wk_s   = d_in[5];
    const void* theta  = d_in[6];
    const void* tconvw = d_in[7];
    const void* tconvb = d_in[8];
    const void* rconvw = d_in[9];
    const void* rconvb = d_in[10];
    const void* ln_g   = d_in[11];
    const void* ln_b   = d_in[12];

    // fixed-region sizes
    const size_t sflag = 256;
    const size_t sqt   = (size_t)BB * TT * NN * 4;   // 1.5 MB (also hosts qs/ks)
    const size_t sta   = 16384;
    const size_t sTt   = 64 * 96 * 2;
    const size_t sWt   = 64 * 224 * 2;
    const size_t sbias = 256;
    const size_t scheb = (size_t)KCH * NN * NN * 2;  // 25.2 MB bf16 cheb
    const size_t fixed = sflag + 2 * sqt + sta + sTt + sWt + sbias + scheb;
    // per-chunk-batch sizes
    const size_t pxT  = (size_t)384 * NN * 2;          // 1.5 MiB
    const size_t psa  = (size_t)NN * NN * 2;           // 8.0 MiB (hosts G too: 3 MiB)
    const size_t prhs = (size_t)NN * TT * 96 * 2;      // 4.5 MiB
    const size_t perb = pxT + psa + prhs;

    int chk = 0;
    for (int c = 16; c >= 1; c >>= 1)
        if (fixed + (size_t)c * perb <= ws_size) { chk = c; break; }

    if (chk == 0) {
        k_emergency<<<(out_size + 255) / 256, 256, 0, stream>>>(
            (__hip_bfloat16*)d_out, (size_t)out_size);
        return;
    }

    char* ws = (char*)d_ws;
    size_t off = 0;
    int*   flag = (int*)(ws + off);             off += sflag;
    float* qt   = (float*)(ws + off);           off += sqt;
    float* kt   = (float*)(ws + off);           off += sqt;
    float* ta   = (float*)(ws + off);           off += sta;
    __hip_bfloat16* Tt = (__hip_bfloat16*)(ws + off);  off += sTt;
    __hip_bfloat16* Wt = (__hip_bfloat16*)(ws + off);  off += sWt;
    float* biasC = (float*)(ws + off);          off += sbias;
    __hip_bfloat16* chebBF = (__hip_bfloat16*)(ws + off); off += scheb;
    __hip_bfloat16* xTc  = (__hip_bfloat16*)(ws + off); off += (size_t)chk * pxT;
    __hip_bfloat16* saC  = (__hip_bfloat16*)(ws + off); off += (size_t)chk * psa;
    __hip_bfloat16* rhsC = (__hip_bfloat16*)(ws + off); off += (size_t)chk * prhs;
    // aliases (lifetimes disjoint):
    float* qs = qt;                 // qt/kt dead after k_tattn
    float* ks = kt;
    __hip_bfloat16* Gc = saC;       // sa dead after k_gemm_cheb; G (chk*3MiB) fits

    k_detect<<<1, 256, 0, stream>>>(x, flag);
    k_cvt_cheb<<<(KCH * NN * NN) / 2048, 256, 0, stream>>>(cheb, flag, chebBF);
    k_prep<<<56, 256, 0, stream>>>(theta, tconvw, tconvb, rconvw, rconvb, flag, Tt, Wt, biasC);
    k_qtkt<<<(BB * TT * NN) / 256, 256, 0, stream>>>(x, wq_t, wk_t, flag, qt, kt);
    k_tattn<<<BB * TT, 256, 0, stream>>>(qt, kt, ta);
    for (int b0 = 0; b0 < BB; b0 += chk) {
        k_xta<<<(chk * NN * 4) / 256, 256, 0, stream>>>(x, ta, wq_s, wk_s, flag, xTc, qs, ks, b0);
        k_sattn<<<chk * (NN / 8), 256, 0, stream>>>(qs, ks, saC, b0);
        k_gemm_cheb<<<dim3(64, chk * KCH), 256, 0, stream>>>(chebBF, saC, xTc, rhsC);
        k_theta<<<(chk * NN * TT) / 128, 256, 0, stream>>>(rhsC, Tt, Gc);
        k_final<<<dim3(NN / 128, TT, chk), 256, 0, stream>>>(Gc, x, Wt, biasC, ln_g, ln_b, flag, d_out, b0);
    }
}

// Round 7
// 688.017 us; speedup vs baseline: 2.1616x; 2.1616x over previous
//
#include <hip/hip_runtime.h>
#include <hip/hip_bf16.h>
#include <math.h>

// Problem constants
#define BB 16
#define TT 12
#define NN 2048
#define FIN 32
#define FOUT 64
#define KCH 3

typedef __attribute__((ext_vector_type(8))) short vbf16x8;
typedef __attribute__((ext_vector_type(4))) float vf32x4;

// ---- dual-mode loads: mf=0 -> data is bf16, mf=1 -> data is fp32 ----------
__device__ __forceinline__ float ldf(const void* p, size_t i, int mf) {
    if (mf) return ((const float*)p)[i];
    return __bfloat162float(((const __hip_bfloat16*)p)[i]);
}

__device__ __forceinline__ void load8d(const void* p, size_t i, int mf, float* o) {
    if (mf) {
        const float* fp = (const float*)p + i;
        float4 a = *(const float4*)fp;
        float4 b = *(const float4*)(fp + 4);
        o[0] = a.x; o[1] = a.y; o[2] = a.z; o[3] = a.w;
        o[4] = b.x; o[5] = b.y; o[6] = b.z; o[7] = b.w;
    } else {
        uint4 u = *(const uint4*)((const __hip_bfloat16*)p + i);
        const __hip_bfloat16* h = (const __hip_bfloat16*)&u;
#pragma unroll
        for (int j = 0; j < 8; ++j) o[j] = __bfloat162float(h[j]);
    }
}

__device__ __forceinline__ vbf16x8 pack8(const float* v) {
    union { vbf16x8 f; __hip_bfloat16 h[8]; } u;
#pragma unroll
    for (int j = 0; j < 8; ++j) u.h[j] = __float2bfloat16(v[j]);
    return u.f;
}

// elementwise bf16 product of two uint4-packed 8-vectors
__device__ __forceinline__ uint4 mulpack8u(uint4 c, uint4 s) {
    const __hip_bfloat16* ch = (const __hip_bfloat16*)&c;
    const __hip_bfloat16* sh = (const __hip_bfloat16*)&s;
    union { uint4 u; __hip_bfloat16 h[8]; } o;
#pragma unroll
    for (int j = 0; j < 8; ++j)
        o.h[j] = __float2bfloat16(__bfloat162float(ch[j]) * __bfloat162float(sh[j]));
    return o.u;
}

// ---------------------------------------------------------------------------
// Detect input dtype (bf16 vs fp32 read as halfwords). flag: 0=bf16, 1=fp32.
// ---------------------------------------------------------------------------
__global__ __launch_bounds__(256) void k_detect(const void* __restrict__ x, int* __restrict__ flag) {
    __shared__ int cnt[256];
    const unsigned short* h = (const unsigned short*)x;
    int bad = 0;
    for (int i = threadIdx.x; i < 4096; i += 256) {
        int e = (h[i] >> 7) & 0xFF;
        if (e < 110 || e > 133) bad++;
    }
    cnt[threadIdx.x] = bad;
    __syncthreads();
    for (int s = 128; s > 0; s >>= 1) {
        if ((int)threadIdx.x < s) cnt[threadIdx.x] += cnt[threadIdx.x + s];
        __syncthreads();
    }
    if (threadIdx.x == 0) flag[0] = (cnt[0] > 614) ? 1 : 0;  // >15% bad => fp32
}

// Emergency: workspace too small — loud sentinel.
__global__ __launch_bounds__(256) void k_emergency(__hip_bfloat16* out, size_t n) {
    size_t i = (size_t)blockIdx.x * 256 + threadIdx.x;
    if (i < n) out[i] = __float2bfloat16(55555.f);
}

// ---------------------------------------------------------------------------
// Convert cheb (fp32 or bf16) -> bf16 contiguous. 8 elems/thread.
// ---------------------------------------------------------------------------
__global__ __launch_bounds__(256) void k_cvt_cheb(
    const void* __restrict__ cheb, const int* __restrict__ flag,
    __hip_bfloat16* __restrict__ chebBF) {
    int mf = flag[0];
    size_t i = ((size_t)blockIdx.x * 256 + threadIdx.x) * 8;
    float v[8];
    load8d(cheb, i, mf, v);
    union { uint4 u; __hip_bfloat16 h[8]; } pv;
#pragma unroll
    for (int j = 0; j < 8; ++j) pv.h[j] = __float2bfloat16(v[j]);
    *reinterpret_cast<uint4*>(&chebBF[i]) = pv.u;
}

// ---------------------------------------------------------------------------
// Prep: Theta^T (64 x 96), Wcat^T (64 x 224), biasC (64)
// ---------------------------------------------------------------------------
__global__ __launch_bounds__(256) void k_prep(
    const void* __restrict__ theta, const void* __restrict__ tconv_w,
    const void* __restrict__ tconv_b, const void* __restrict__ rconv_w,
    const void* __restrict__ rconv_b, const int* __restrict__ flag,
    __hip_bfloat16* __restrict__ Tt, __hip_bfloat16* __restrict__ Wt, float* __restrict__ biasC) {
    int mf = flag[0];
    int tid = blockIdx.x * 256 + threadIdx.x;
    if (tid < 64 * 96) {  // Tt[o][kf] = theta[kf*64 + o]
        int o = tid / 96, kf = tid % 96;
        Tt[tid] = __float2bfloat16(ldf(theta, (size_t)kf * 64 + o, mf));
    }
    if (tid < 64 * 224) {  // Wt[o][c]
        int o = tid / 224, c = tid % 224;
        float v;
        if (c < 192) {
            int dt = c / 64, i = c % 64;
            v = ldf(tconv_w, ((size_t)o * 64 + i) * 3 + dt, mf);
        } else {
            v = ldf(rconv_w, (size_t)o * 32 + (c - 192), mf);
        }
        Wt[tid] = __float2bfloat16(v);
    }
    if (tid < 64) biasC[tid] = ldf(tconv_b, tid, mf) + ldf(rconv_b, tid, mf);
}

// ---------------------------------------------------------------------------
// K1: qt/kt  (B,T,N) fp32
// ---------------------------------------------------------------------------
__global__ __launch_bounds__(256) void k_qtkt(
    const void* __restrict__ x, const void* __restrict__ wq,
    const void* __restrict__ wk, const int* __restrict__ flag,
    float* __restrict__ qt, float* __restrict__ kt) {
    int mf = flag[0];
    __shared__ float swq[32], swk[32];
    if (threadIdx.x < 32) swq[threadIdx.x] = ldf(wq, threadIdx.x, mf);
    else if (threadIdx.x < 64) swk[threadIdx.x - 32] = ldf(wk, threadIdx.x - 32, mf);
    __syncthreads();
    size_t idx = (size_t)blockIdx.x * 256 + threadIdx.x;  // (b*T+t)*N+n
    float q = 0.f, k = 0.f;
#pragma unroll
    for (int c = 0; c < 4; ++c) {
        float v[8];
        load8d(x, idx * FIN + c * 8, mf, v);
#pragma unroll
        for (int j = 0; j < 8; ++j) { q += v[j] * swq[c * 8 + j]; k += v[j] * swk[c * 8 + j]; }
    }
    qt[idx] = q;
    kt[idx] = k;
}

// ---------------------------------------------------------------------------
// K2: temporal scores + softmax -> ta (B,T,T) fp32. One block per (b,t).
// ---------------------------------------------------------------------------
__global__ __launch_bounds__(256) void k_tattn(
    const float* __restrict__ qt, const float* __restrict__ kt, float* __restrict__ ta) {
    int b = blockIdx.x / TT, t = blockIdx.x % TT;
    const float* q = qt + ((size_t)b * TT + t) * NN;
    float part[TT];
#pragma unroll
    for (int s = 0; s < TT; ++s) part[s] = 0.f;
    for (int n = threadIdx.x; n < NN; n += 256) {
        float qv = q[n];
#pragma unroll
        for (int s = 0; s < TT; ++s) part[s] += qv * kt[((size_t)b * TT + s) * NN + n];
    }
    __shared__ float red[TT][4];
    __shared__ float sc[TT];
    int lane = threadIdx.x & 63, wid = threadIdx.x >> 6;
#pragma unroll
    for (int s = 0; s < TT; ++s) {
        float v = part[s];
#pragma unroll
        for (int m = 32; m >= 1; m >>= 1) v += __shfl_xor(v, m);
        if (lane == 0) red[s][wid] = v;
    }
    __syncthreads();
    if (threadIdx.x < TT)
        sc[threadIdx.x] = (red[threadIdx.x][0] + red[threadIdx.x][1] + red[threadIdx.x][2] +
                           red[threadIdx.x][3]) * 0.02209708691207961f;  // 1/sqrt(2048)
    __syncthreads();
    if (threadIdx.x == 0) {
        float m = sc[0];
#pragma unroll
        for (int s = 1; s < TT; ++s) m = fmaxf(m, sc[s]);
        float e[TT], sum = 0.f;
#pragma unroll
        for (int s = 0; s < TT; ++s) { e[s] = __expf(sc[s] - m); sum += e[s]; }
        float inv = 1.f / sum;
#pragma unroll
        for (int s = 0; s < TT; ++s) ta[((size_t)b * TT + t) * TT + s] = e[s] * inv;
    }
}

// ---------------------------------------------------------------------------
// K3 (per chunk): x_ta -> xT_c[bl][t*32+f][n] (bf16); qs/ks (global b) fused.
// ---------------------------------------------------------------------------
__global__ __launch_bounds__(256) void k_xta(
    const void* __restrict__ x, const float* __restrict__ ta,
    const void* __restrict__ wqs, const void* __restrict__ wks, const int* __restrict__ flag,
    __hip_bfloat16* __restrict__ xT, float* __restrict__ qs, float* __restrict__ ks, int b0) {
    int mf = flag[0];
    int gid = blockIdx.x * 256 + threadIdx.x;
    int fg = gid & 3;
    int n = (gid >> 2) & (NN - 1);
    int bl = gid >> 13;          // 0..chk-1 (block-uniform)
    int b = b0 + bl;
    __shared__ float sta[TT * TT];
    __shared__ float swq[32], swk[32];
    if (threadIdx.x < 144) sta[threadIdx.x] = ta[(size_t)b * 144 + threadIdx.x];
    else if (threadIdx.x >= 160 && threadIdx.x < 192) swq[threadIdx.x - 160] = ldf(wqs, threadIdx.x - 160, mf);
    else if (threadIdx.x >= 192 && threadIdx.x < 224) swk[threadIdx.x - 192] = ldf(wks, threadIdx.x - 192, mf);
    __syncthreads();

    float acc[TT][8];
#pragma unroll
    for (int t = 0; t < TT; ++t)
#pragma unroll
        for (int j = 0; j < 8; ++j) acc[t][j] = 0.f;

    for (int s = 0; s < TT; ++s) {
        float xv[8];
        load8d(x, (((size_t)(b * TT + s) * NN) + n) * FIN + fg * 8, mf, xv);
#pragma unroll
        for (int t = 0; t < TT; ++t) {
            float w = sta[t * TT + s];
#pragma unroll
            for (int j = 0; j < 8; ++j) acc[t][j] += w * xv[j];
        }
    }
    size_t xbase = (size_t)bl * 384 * NN;
#pragma unroll
    for (int t = 0; t < TT; ++t)
#pragma unroll
        for (int j = 0; j < 8; ++j)
            xT[xbase + (size_t)(t * 32 + fg * 8 + j) * NN + n] = __float2bfloat16(acc[t][j]);
#pragma unroll
    for (int t = 0; t < TT; ++t) {
        float pq = 0.f, pk = 0.f;
#pragma unroll
        for (int j = 0; j < 8; ++j) {
            pq += acc[t][j] * swq[fg * 8 + j];
            pk += acc[t][j] * swk[fg * 8 + j];
        }
        pq += __shfl_xor(pq, 1); pq += __shfl_xor(pq, 2);
        pk += __shfl_xor(pk, 1); pk += __shfl_xor(pk, 2);
        if (fg == 0) {
            qs[((size_t)b * NN + n) * TT + t] = pq;
            ks[((size_t)b * NN + n) * TT + t] = pk;
        }
    }
}

// ---------------------------------------------------------------------------
// K5 (per chunk): sa_c[bl][i][j] (bf16), softmax over j. 8 i-rows / block.
// ---------------------------------------------------------------------------
__global__ __launch_bounds__(256) void k_sattn(
    const float* __restrict__ qs, const float* __restrict__ ks,
    __hip_bfloat16* __restrict__ sa, int b0) {
    int bl = blockIdx.x >> 8;
    int b = b0 + bl;
    int i0 = (blockIdx.x & 255) * 8;
    __shared__ float qrow[8][TT];
    __shared__ float rbuf[4];
    if (threadIdx.x < 96) qrow[threadIdx.x / TT][threadIdx.x % TT] =
        qs[((size_t)b * NN + i0) * TT + threadIdx.x];
    __syncthreads();
    const float scale = 0.28867513459481287f;  // 1/sqrt(12)
    float sc[8][8];
#pragma unroll
    for (int c = 0; c < 8; ++c) {
        int j = threadIdx.x + (c << 8);
        const float* kr = ks + ((size_t)b * NN + j) * TT;
        float kv[TT];
        *(float4*)&kv[0] = *(const float4*)&kr[0];
        *(float4*)&kv[4] = *(const float4*)&kr[4];
        *(float4*)&kv[8] = *(const float4*)&kr[8];
#pragma unroll
        for (int r = 0; r < 8; ++r) {
            float d = 0.f;
#pragma unroll
            for (int t = 0; t < TT; ++t) d += qrow[r][t] * kv[t];
            sc[r][c] = d * scale;
        }
    }
    int lane = threadIdx.x & 63, wid = threadIdx.x >> 6;
#pragma unroll
    for (int r = 0; r < 8; ++r) {
        float v = -1e30f;
#pragma unroll
        for (int c = 0; c < 8; ++c) v = fmaxf(v, sc[r][c]);
#pragma unroll
        for (int m = 32; m >= 1; m >>= 1) v = fmaxf(v, __shfl_xor(v, m));
        if (lane == 0) rbuf[wid] = v;
        __syncthreads();
        float bmax = fmaxf(fmaxf(rbuf[0], rbuf[1]), fmaxf(rbuf[2], rbuf[3]));
        __syncthreads();
        float lsum = 0.f;
#pragma unroll
        for (int c = 0; c < 8; ++c) { float e = __expf(sc[r][c] - bmax); sc[r][c] = e; lsum += e; }
        v = lsum;
#pragma unroll
        for (int m = 32; m >= 1; m >>= 1) v += __shfl_xor(v, m);
        if (lane == 0) rbuf[wid] = v;
        __syncthreads();
        float inv = 1.f / (rbuf[0] + rbuf[1] + rbuf[2] + rbuf[3]);
        __syncthreads();
        size_t base = ((size_t)bl * NN + i0 + r) * NN + threadIdx.x;
#pragma unroll
        for (int c = 0; c < 8; ++c) sa[base + (c << 8)] = __float2bfloat16(sc[r][c] * inv);
    }
}

// ---------------------------------------------------------------------------
// K6 (per chunk): per (bl,kk):  C = (chebBF_k .* sa_bl) @ X_bl -> rhs_c
//   M=2048(i), N=384(all tf), K=2048(j).
//   r6: BK=64 (32 steps, was 64). r2-r5 established: not BW-bound (12% HBM),
//   not occupancy-bound (r4), not load-placement (r3), LDS coalescing is
//   load-bearing (r5: removing it = 16-line splits = 3.5x worse). Residual
//   theory: per-step FIXED cost (barrier + exposed L3/HBM latency of sa/cheb
//   prefetch, ~900cyc vs ~470cyc MFMA cover). BK=64 doubles MFMA cover per
//   step (~930cyc >= latency) and halves the number of exposed events.
//   Two-phase B pipeline (bA/bB, static regs) removes the bcur<-bnxt copy's
//   within-step vmcnt stall. A-stage now 8 lanes/row (8-line splits, was 16).
//   LDS As[2][64][72] = 18.4KB; 2 blocks/CU via registers (~130V+96A).
// ---------------------------------------------------------------------------
__global__ __launch_bounds__(256, 2) void k_gemm_cheb(
    const __hip_bfloat16* __restrict__ chebBF, const __hip_bfloat16* __restrict__ sa,
    const __hip_bfloat16* __restrict__ xT, __hip_bfloat16* __restrict__ rhs) {
    int it = blockIdx.x;        // i tile 0..31 (64 rows each)
    int bz = blockIdx.y;        // 0..3*chk-1
    int bl = bz / 3, kk = bz % 3;

    __shared__ __hip_bfloat16 As[2][64][72];

    int tid = threadIdx.x;
    int wid = tid >> 6, lane = tid & 63;
    int wn = wid * 96;
    int lr = lane & 15, kq = (lane >> 4) * 8;

    const size_t i0 = (size_t)it * 64;
    const __hip_bfloat16* chebK = chebBF + (size_t)kk * NN * NN;
    const __hip_bfloat16* saB = sa + (size_t)bl * NN * NN;
    const __hip_bfloat16* xTB = xT + (size_t)bl * 384 * NN;

    int srow = tid >> 3;          // 0..31 (rows srow and srow+32)
    int scol = (tid & 7) * 8;     // 0..56

    const __hip_bfloat16* cptr = &chebK[(i0 + srow) * NN + scol];
    const __hip_bfloat16* sptr = &saB[(i0 + srow) * NN + scol];
    const __hip_bfloat16* bptr = &xTB[(size_t)(wn + lr) * NN + kq];

    vf32x4 acc[4][6];
    vf32x4 z4 = {0.f, 0.f, 0.f, 0.f};
#pragma unroll
    for (int mi = 0; mi < 4; ++mi)
#pragma unroll
        for (int ni = 0; ni < 6; ++ni) acc[mi][ni] = z4;

    // prologue: A regs (step 0) + B ks0 frags (step 0)
    uint4 cu[2], su[2];
    cu[0] = *reinterpret_cast<const uint4*>(cptr);
    cu[1] = *reinterpret_cast<const uint4*>(cptr + (size_t)32 * NN);
    su[0] = *reinterpret_cast<const uint4*>(sptr);
    su[1] = *reinterpret_cast<const uint4*>(sptr + (size_t)32 * NN);
    vbf16x8 bA[6], bB[6];
#pragma unroll
    for (int ni = 0; ni < 6; ++ni)
        bA[ni] = *reinterpret_cast<const vbf16x8*>(bptr + (size_t)(ni * 16) * NN);

    for (int step = 0; step < 32; ++step) {
        int p = step & 1;
        size_t kbase = (size_t)step * 64;
        // A-product (this step, from regs) -> LDS
        {
            uint4 p0 = mulpack8u(cu[0], su[0]);
            uint4 p1 = mulpack8u(cu[1], su[1]);
            *reinterpret_cast<uint4*>(&As[p][srow][scol]) = p0;
            *reinterpret_cast<uint4*>(&As[p][srow + 32][scol]) = p1;
        }
        __syncthreads();

        // a-frags for both k-subgroups
        vbf16x8 a0[4], a1[4];
#pragma unroll
        for (int mi = 0; mi < 4; ++mi)
            a0[mi] = *reinterpret_cast<const vbf16x8*>(&As[p][mi * 16 + lr][kq]);
#pragma unroll
        for (int mi = 0; mi < 4; ++mi)
            a1[mi] = *reinterpret_cast<const vbf16x8*>(&As[p][mi * 16 + lr][32 + kq]);

        // issue next-step A loads (covered by both MFMA phases + barrier)
        size_t kn = (step < 31) ? kbase + 64 : kbase;  // tail clamp, values unused
        cu[0] = *reinterpret_cast<const uint4*>(cptr + kn);
        cu[1] = *reinterpret_cast<const uint4*>(cptr + (size_t)32 * NN + kn);
        su[0] = *reinterpret_cast<const uint4*>(sptr + kn);
        su[1] = *reinterpret_cast<const uint4*>(sptr + (size_t)32 * NN + kn);

        // issue B ks1 (this step) — covered by ks0 MFMA block
#pragma unroll
        for (int ni = 0; ni < 6; ++ni)
            bB[ni] = *reinterpret_cast<const vbf16x8*>(bptr + (size_t)(ni * 16) * NN + kbase + 32);

        // MFMA phase ks0
#pragma unroll
        for (int ni = 0; ni < 6; ++ni)
#pragma unroll
            for (int mi = 0; mi < 4; ++mi)
                acc[mi][ni] = __builtin_amdgcn_mfma_f32_16x16x32_bf16(a0[mi], bA[ni], acc[mi][ni], 0, 0, 0);

        // issue B ks0 (next step) — covered by ks1 MFMA block
#pragma unroll
        for (int ni = 0; ni < 6; ++ni)
            bA[ni] = *reinterpret_cast<const vbf16x8*>(bptr + (size_t)(ni * 16) * NN + kn);

        // MFMA phase ks1
#pragma unroll
        for (int ni = 0; ni < 6; ++ni)
#pragma unroll
            for (int mi = 0; mi < 4; ++mi)
                acc[mi][ni] = __builtin_amdgcn_mfma_f32_16x16x32_bf16(a1[mi], bB[ni], acc[mi][ni], 0, 0, 0);
        // As[p] rewritten only at step+2, after the step+1 barrier drained
        // all step reads — single barrier per step is safe.
    }

    // epilogue: row = mi*16 + quad*4 + g; col = wn + ni*16 + lr
#pragma unroll
    for (int mi = 0; mi < 4; ++mi)
#pragma unroll
        for (int ni = 0; ni < 6; ++ni)
#pragma unroll
            for (int g = 0; g < 4; ++g) {
                int row = mi * 16 + ((lane >> 4) << 2) + g;
                int col = wn + ni * 16 + lr;
                size_t i = i0 + row;
                int t = col >> 5, f = col & 31;
                rhs[(((size_t)bl * NN + i) * TT + t) * 96 + kk * 32 + f] =
                    __float2bfloat16(acc[mi][ni][g]);
            }
}

// ---------------------------------------------------------------------------
// K7a (per chunk): G = relu(rhs @ Theta)  rows (bl,n,t), K=96, N=64
//      G stored [bl][t][n][o] bf16
// ---------------------------------------------------------------------------
__global__ __launch_bounds__(256) void k_theta(
    const __hip_bfloat16* __restrict__ rhs, const __hip_bfloat16* __restrict__ Tt,
    __hip_bfloat16* __restrict__ G) {
    __shared__ __hip_bfloat16 Ts[64][104];
    int tid = threadIdx.x;
    int srow = tid >> 2, scol = (tid & 3) * 8;
#pragma unroll
    for (int c0 = 0; c0 < 96; c0 += 32)
        *reinterpret_cast<uint4*>(&Ts[srow][c0 + scol]) =
            *reinterpret_cast<const uint4*>(&Tt[(size_t)srow * 96 + c0 + scol]);
    __syncthreads();
    int wid = tid >> 6, lane = tid & 63;
    int lr = lane & 15, kq = (lane >> 4) * 8;
    size_t r0 = (size_t)blockIdx.x * 128 + wid * 32;
    vf32x4 acc[2][4];
    vf32x4 z4 = {0.f, 0.f, 0.f, 0.f};
#pragma unroll
    for (int mi = 0; mi < 2; ++mi)
#pragma unroll
        for (int ni = 0; ni < 4; ++ni) acc[mi][ni] = z4;
#pragma unroll
    for (int s = 0; s < 3; ++s) {
        vbf16x8 a[2], bf[4];
#pragma unroll
        for (int mi = 0; mi < 2; ++mi)
            a[mi] = *reinterpret_cast<const vbf16x8*>(&rhs[(r0 + mi * 16 + lr) * 96 + s * 32 + kq]);
#pragma unroll
        for (int ni = 0; ni < 4; ++ni)
            bf[ni] = *reinterpret_cast<const vbf16x8*>(&Ts[ni * 16 + lr][s * 32 + kq]);
#pragma unroll
        for (int mi = 0; mi < 2; ++mi)
#pragma unroll
            for (int ni = 0; ni < 4; ++ni)
                acc[mi][ni] = __builtin_amdgcn_mfma_f32_16x16x32_bf16(a[mi], bf[ni], acc[mi][ni], 0, 0, 0);
    }
#pragma unroll
    for (int mi = 0; mi < 2; ++mi)
#pragma unroll
        for (int ni = 0; ni < 4; ++ni)
#pragma unroll
            for (int g = 0; g < 4; ++g) {
                size_t r = r0 + mi * 16 + ((lane >> 4) << 2) + g;  // (bl*N+n)*T+t
                int col = ni * 16 + (lane & 15);
                int t = (int)(r % TT);
                size_t bn = r / TT;
                int n = (int)(bn & (NN - 1));
                int bl = (int)(bn >> 11);
                float v = fmaxf(acc[mi][ni][g], 0.f);
                G[(((size_t)bl * TT + t) * NN + n) * 64 + col] = __float2bfloat16(v);
            }
}

// ---------------------------------------------------------------------------
// K7b (per chunk): y = relu([G(t-1),G(t),G(t+1),x] @ Wcat + bias); LayerNorm
//      block = (nblk, t, bl); 128 rows (n), K=224, N=64
// ---------------------------------------------------------------------------
__global__ __launch_bounds__(256) void k_final(
    const __hip_bfloat16* __restrict__ G, const void* __restrict__ x,
    const __hip_bfloat16* __restrict__ Wt, const float* __restrict__ biasC,
    const void* __restrict__ ln_g, const void* __restrict__ ln_b,
    const int* __restrict__ flag, void* __restrict__ outv, int b0) {
    int mf = flag[0];
    int n0 = blockIdx.x * 128;
    int t = blockIdx.y;
    int bl = blockIdx.z;
    int b = b0 + bl;
    __shared__ __hip_bfloat16 Ws[64][232];
    __shared__ float sg[64], sb[64], sbias[64];
    int tid = threadIdx.x;
    int srow = tid >> 2, scol = (tid & 3) * 8;
#pragma unroll
    for (int c0 = 0; c0 < 224; c0 += 32)
        *reinterpret_cast<uint4*>(&Ws[srow][c0 + scol]) =
            *reinterpret_cast<const uint4*>(&Wt[(size_t)srow * 224 + c0 + scol]);
    if (tid < 64) {
        sg[tid] = ldf(ln_g, tid, mf);
        sb[tid] = ldf(ln_b, tid, mf);
        sbias[tid] = biasC[tid];
    }
    __syncthreads();
    int wid = tid >> 6, lane = tid & 63;
    int lr = lane & 15, kq = (lane >> 4) * 8;
    int rw = n0 + wid * 32;
    vf32x4 acc[2][4];
    vf32x4 z4 = {0.f, 0.f, 0.f, 0.f};
#pragma unroll
    for (int mi = 0; mi < 2; ++mi)
#pragma unroll
        for (int ni = 0; ni < 4; ++ni) acc[mi][ni] = z4;

    vbf16x8 zfrag = {0, 0, 0, 0, 0, 0, 0, 0};
#pragma unroll
    for (int s = 0; s < 7; ++s) {
        int kb = s * 32;
        vbf16x8 a[2], bf[4];
#pragma unroll
        for (int ni = 0; ni < 4; ++ni)
            bf[ni] = *reinterpret_cast<const vbf16x8*>(&Ws[ni * 16 + lr][kb + kq]);
        if (s < 6) {
            int dt = s >> 1;
            int t2 = t + dt - 1;
            int off = (s & 1) * 32 + kq;
            if (t2 >= 0 && t2 < TT) {
#pragma unroll
                for (int mi = 0; mi < 2; ++mi)
                    a[mi] = *reinterpret_cast<const vbf16x8*>(
                        &G[(((size_t)bl * TT + t2) * NN + rw + mi * 16 + lr) * 64 + off]);
            } else {
                a[0] = zfrag; a[1] = zfrag;
            }
        } else {
#pragma unroll
            for (int mi = 0; mi < 2; ++mi) {
                float xv[8];
                load8d(x, (((size_t)b * TT + t) * NN + rw + mi * 16 + lr) * FIN + kq, mf, xv);
                a[mi] = pack8(xv);
            }
        }
#pragma unroll
        for (int mi = 0; mi < 2; ++mi)
#pragma unroll
            for (int ni = 0; ni < 4; ++ni)
                acc[mi][ni] = __builtin_amdgcn_mfma_f32_16x16x32_bf16(a[mi], bf[ni], acc[mi][ni], 0, 0, 0);
    }
    float vals[2][4][4];
#pragma unroll
    for (int mi = 0; mi < 2; ++mi)
#pragma unroll
        for (int ni = 0; ni < 4; ++ni) {
            int col = ni * 16 + lr;
#pragma unroll
            for (int g = 0; g < 4; ++g)
                vals[mi][ni][g] = fmaxf(acc[mi][ni][g] + sbias[col], 0.f);
        }
#pragma unroll
    for (int mi = 0; mi < 2; ++mi)
#pragma unroll
        for (int g = 0; g < 4; ++g) {
            float s1 = 0.f, s2 = 0.f;
#pragma unroll
            for (int ni = 0; ni < 4; ++ni) { float v = vals[mi][ni][g]; s1 += v; s2 += v * v; }
            s1 += __shfl_xor(s1, 1); s2 += __shfl_xor(s2, 1);
            s1 += __shfl_xor(s1, 2); s2 += __shfl_xor(s2, 2);
            s1 += __shfl_xor(s1, 4); s2 += __shfl_xor(s2, 4);
            s1 += __shfl_xor(s1, 8); s2 += __shfl_xor(s2, 8);
            float mean = s1 * (1.f / 64.f);
            float var = fmaxf(s2 * (1.f / 64.f) - mean * mean, 0.f);
            float rstd = rsqrtf(var + 1e-5f);
            int row = wid * 32 + mi * 16 + ((lane >> 4) << 2) + g;
#pragma unroll
            for (int ni = 0; ni < 4; ++ni) {
                int col = ni * 16 + lr;
                float y = (vals[mi][ni][g] - mean) * rstd * sg[col] + sb[col];
                size_t oi = (((size_t)b * TT + t) * NN + n0 + row) * 64 + col;
                if (mf) ((float*)outv)[oi] = y;
                else ((__hip_bfloat16*)outv)[oi] = __float2bfloat16(y);
            }
        }
}

// ---------------------------------------------------------------------------
extern "C" void kernel_launch(void* const* d_in, const int* in_sizes, int n_in,
                              void* d_out, int out_size, void* d_ws, size_t ws_size,
                              hipStream_t stream) {
    const void* x      = d_in[0];
    const void* cheb   = d_in[1];
    const void* wq_t   = d_in[2];
    const void* wk_t   = d_in[3];
    const void* wq_s   = d_in[4];
    const void* wk_s   = d_in[5];
    const void* theta  = d_in[6];
    const void* tconvw = d_in[7];
    const void* tconvb = d_in[8];
    const void* rconvw = d_in[9];
    const void* rconvb = d_in[10];
    const void* ln_g   = d_in[11];
    const void* ln_b   = d_in[12];

    // fixed-region sizes
    const size_t sflag = 256;
    const size_t sqt   = (size_t)BB * TT * NN * 4;   // 1.5 MB (also hosts qs/ks)
    const size_t sta   = 16384;
    const size_t sTt   = 64 * 96 * 2;
    const size_t sWt   = 64 * 224 * 2;
    const size_t sbias = 256;
    const size_t scheb = (size_t)KCH * NN * NN * 2;  // 25.2 MB bf16 cheb
    const size_t fixed = sflag + 2 * sqt + sta + sTt + sWt + sbias + scheb;
    // per-chunk-batch sizes
    const size_t pxT  = (size_t)384 * NN * 2;          // 1.5 MiB
    const size_t psa  = (size_t)NN * NN * 2;           // 8.0 MiB (hosts G too: 3 MiB)
    const size_t prhs = (size_t)NN * TT * 96 * 2;      // 4.5 MiB
    const size_t perb = pxT + psa + prhs;

    int chk = 0;
    for (int c = 16; c >= 1; c >>= 1)
        if (fixed + (size_t)c * perb <= ws_size) { chk = c; break; }

    if (chk == 0) {
        k_emergency<<<(out_size + 255) / 256, 256, 0, stream>>>(
            (__hip_bfloat16*)d_out, (size_t)out_size);
        return;
    }

    char* ws = (char*)d_ws;
    size_t off = 0;
    int*   flag = (int*)(ws + off);             off += sflag;
    float* qt   = (float*)(ws + off);           off += sqt;
    float* kt   = (float*)(ws + off);           off += sqt;
    float* ta   = (float*)(ws + off);           off += sta;
    __hip_bfloat16* Tt = (__hip_bfloat16*)(ws + off);  off += sTt;
    __hip_bfloat16* Wt = (__hip_bfloat16*)(ws + off);  off += sWt;
    float* biasC = (float*)(ws + off);          off += sbias;
    __hip_bfloat16* chebBF = (__hip_bfloat16*)(ws + off); off += scheb;
    __hip_bfloat16* xTc  = (__hip_bfloat16*)(ws + off); off += (size_t)chk * pxT;
    __hip_bfloat16* saC  = (__hip_bfloat16*)(ws + off); off += (size_t)chk * psa;
    __hip_bfloat16* rhsC = (__hip_bfloat16*)(ws + off); off += (size_t)chk * prhs;
    // aliases (lifetimes disjoint):
    float* qs = qt;                 // qt/kt dead after k_tattn
    float* ks = kt;
    __hip_bfloat16* Gc = saC;       // sa dead after k_gemm_cheb; G (chk*3MiB) fits

    k_detect<<<1, 256, 0, stream>>>(x, flag);
    k_cvt_cheb<<<(KCH * NN * NN) / 2048, 256, 0, stream>>>(cheb, flag, chebBF);
    k_prep<<<56, 256, 0, stream>>>(theta, tconvw, tconvb, rconvw, rconvb, flag, Tt, Wt, biasC);
    k_qtkt<<<(BB * TT * NN) / 256, 256, 0, stream>>>(x, wq_t, wk_t, flag, qt, kt);
    k_tattn<<<BB * TT, 256, 0, stream>>>(qt, kt, ta);
    for (int b0 = 0; b0 < BB; b0 += chk) {
        k_xta<<<(chk * NN * 4) / 256, 256, 0, stream>>>(x, ta, wq_s, wk_s, flag, xTc, qs, ks, b0);
        k_sattn<<<chk * (NN / 8), 256, 0, stream>>>(qs, ks, saC, b0);
        k_gemm_cheb<<<dim3(32, chk * KCH), 256, 0, stream>>>(chebBF, saC, xTc, rhsC);
        k_theta<<<(chk * NN * TT) / 128, 256, 0, stream>>>(rhsC, Tt, Gc);
        k_final<<<dim3(NN / 128, TT, chk), 256, 0, stream>>>(Gc, x, Wt, biasC, ln_g, ln_b, flag, d_out, b0);
    }
}

// Round 9
// 630.073 us; speedup vs baseline: 2.3603x; 1.0920x over previous
//
#include <hip/hip_runtime.h>
#include <hip/hip_bf16.h>
#include <math.h>

// Problem constants
#define BB 16
#define TT 12
#define NN 2048
#define FIN 32
#define FOUT 64
#define KCH 3

typedef __attribute__((ext_vector_type(8))) short vbf16x8;
typedef __attribute__((ext_vector_type(4))) float vf32x4;

// ---- dual-mode loads: mf=0 -> data is bf16, mf=1 -> data is fp32 ----------
__device__ __forceinline__ float ldf(const void* p, size_t i, int mf) {
    if (mf) return ((const float*)p)[i];
    return __bfloat162float(((const __hip_bfloat16*)p)[i]);
}

__device__ __forceinline__ void load8d(const void* p, size_t i, int mf, float* o) {
    if (mf) {
        const float* fp = (const float*)p + i;
        float4 a = *(const float4*)fp;
        float4 b = *(const float4*)(fp + 4);
        o[0] = a.x; o[1] = a.y; o[2] = a.z; o[3] = a.w;
        o[4] = b.x; o[5] = b.y; o[6] = b.z; o[7] = b.w;
    } else {
        uint4 u = *(const uint4*)((const __hip_bfloat16*)p + i);
        const __hip_bfloat16* h = (const __hip_bfloat16*)&u;
#pragma unroll
        for (int j = 0; j < 8; ++j) o[j] = __bfloat162float(h[j]);
    }
}

__device__ __forceinline__ vbf16x8 pack8(const float* v) {
    union { vbf16x8 f; __hip_bfloat16 h[8]; } u;
#pragma unroll
    for (int j = 0; j < 8; ++j) u.h[j] = __float2bfloat16(v[j]);
    return u.f;
}

// elementwise bf16 product of two uint4-packed 8-vectors
__device__ __forceinline__ uint4 mulpack8u(uint4 c, uint4 s) {
    const __hip_bfloat16* ch = (const __hip_bfloat16*)&c;
    const __hip_bfloat16* sh = (const __hip_bfloat16*)&s;
    union { uint4 u; __hip_bfloat16 h[8]; } o;
#pragma unroll
    for (int j = 0; j < 8; ++j)
        o.h[j] = __float2bfloat16(__bfloat162float(ch[j]) * __bfloat162float(sh[j]));
    return o.u;
}

// async global->LDS DMA, 16B per lane. LDS dest must be wave-uniform base
// (HW writes lane i at base + i*16); global source is per-lane.
__device__ __forceinline__ void gload16(const __hip_bfloat16* g, __hip_bfloat16* l) {
    __builtin_amdgcn_global_load_lds(
        (const __attribute__((address_space(1))) unsigned int*)g,
        (__attribute__((address_space(3))) unsigned int*)l, 16, 0, 0);
}

// ---------------------------------------------------------------------------
// Detect input dtype (bf16 vs fp32 read as halfwords). flag: 0=bf16, 1=fp32.
// ---------------------------------------------------------------------------
__global__ __launch_bounds__(256) void k_detect(const void* __restrict__ x, int* __restrict__ flag) {
    __shared__ int cnt[256];
    const unsigned short* h = (const unsigned short*)x;
    int bad = 0;
    for (int i = threadIdx.x; i < 4096; i += 256) {
        int e = (h[i] >> 7) & 0xFF;
        if (e < 110 || e > 133) bad++;
    }
    cnt[threadIdx.x] = bad;
    __syncthreads();
    for (int s = 128; s > 0; s >>= 1) {
        if ((int)threadIdx.x < s) cnt[threadIdx.x] += cnt[threadIdx.x + s];
        __syncthreads();
    }
    if (threadIdx.x == 0) flag[0] = (cnt[0] > 614) ? 1 : 0;  // >15% bad => fp32
}

// Emergency: workspace too small — loud sentinel.
__global__ __launch_bounds__(256) void k_emergency(__hip_bfloat16* out, size_t n) {
    size_t i = (size_t)blockIdx.x * 256 + threadIdx.x;
    if (i < n) out[i] = __float2bfloat16(55555.f);
}

// ---------------------------------------------------------------------------
// Convert cheb (fp32 or bf16) -> bf16 contiguous. 8 elems/thread.
// ---------------------------------------------------------------------------
__global__ __launch_bounds__(256) void k_cvt_cheb(
    const void* __restrict__ cheb, const int* __restrict__ flag,
    __hip_bfloat16* __restrict__ chebBF) {
    int mf = flag[0];
    size_t i = ((size_t)blockIdx.x * 256 + threadIdx.x) * 8;
    float v[8];
    load8d(cheb, i, mf, v);
    union { uint4 u; __hip_bfloat16 h[8]; } pv;
#pragma unroll
    for (int j = 0; j < 8; ++j) pv.h[j] = __float2bfloat16(v[j]);
    *reinterpret_cast<uint4*>(&chebBF[i]) = pv.u;
}

// ---------------------------------------------------------------------------
// Prep: Theta^T (64 x 96), Wcat^T (64 x 224), biasC (64)
// ---------------------------------------------------------------------------
__global__ __launch_bounds__(256) void k_prep(
    const void* __restrict__ theta, const void* __restrict__ tconv_w,
    const void* __restrict__ tconv_b, const void* __restrict__ rconv_w,
    const void* __restrict__ rconv_b, const int* __restrict__ flag,
    __hip_bfloat16* __restrict__ Tt, __hip_bfloat16* __restrict__ Wt, float* __restrict__ biasC) {
    int mf = flag[0];
    int tid = blockIdx.x * 256 + threadIdx.x;
    if (tid < 64 * 96) {  // Tt[o][kf] = theta[kf*64 + o]
        int o = tid / 96, kf = tid % 96;
        Tt[tid] = __float2bfloat16(ldf(theta, (size_t)kf * 64 + o, mf));
    }
    if (tid < 64 * 224) {  // Wt[o][c]
        int o = tid / 224, c = tid % 224;
        float v;
        if (c < 192) {
            int dt = c / 64, i = c % 64;
            v = ldf(tconv_w, ((size_t)o * 64 + i) * 3 + dt, mf);
        } else {
            v = ldf(rconv_w, (size_t)o * 32 + (c - 192), mf);
        }
        Wt[tid] = __float2bfloat16(v);
    }
    if (tid < 64) biasC[tid] = ldf(tconv_b, tid, mf) + ldf(rconv_b, tid, mf);
}

// ---------------------------------------------------------------------------
// K1: qt/kt  (B,T,N) fp32
// ---------------------------------------------------------------------------
__global__ __launch_bounds__(256) void k_qtkt(
    const void* __restrict__ x, const void* __restrict__ wq,
    const void* __restrict__ wk, const int* __restrict__ flag,
    float* __restrict__ qt, float* __restrict__ kt) {
    int mf = flag[0];
    __shared__ float swq[32], swk[32];
    if (threadIdx.x < 32) swq[threadIdx.x] = ldf(wq, threadIdx.x, mf);
    else if (threadIdx.x < 64) swk[threadIdx.x - 32] = ldf(wk, threadIdx.x - 32, mf);
    __syncthreads();
    size_t idx = (size_t)blockIdx.x * 256 + threadIdx.x;  // (b*T+t)*N+n
    float q = 0.f, k = 0.f;
#pragma unroll
    for (int c = 0; c < 4; ++c) {
        float v[8];
        load8d(x, idx * FIN + c * 8, mf, v);
#pragma unroll
        for (int j = 0; j < 8; ++j) { q += v[j] * swq[c * 8 + j]; k += v[j] * swk[c * 8 + j]; }
    }
    qt[idx] = q;
    kt[idx] = k;
}

// ---------------------------------------------------------------------------
// K2: temporal scores + softmax -> ta (B,T,T) fp32. One block per (b,t).
// ---------------------------------------------------------------------------
__global__ __launch_bounds__(256) void k_tattn(
    const float* __restrict__ qt, const float* __restrict__ kt, float* __restrict__ ta) {
    int b = blockIdx.x / TT, t = blockIdx.x % TT;
    const float* q = qt + ((size_t)b * TT + t) * NN;
    float part[TT];
#pragma unroll
    for (int s = 0; s < TT; ++s) part[s] = 0.f;
    for (int n = threadIdx.x; n < NN; n += 256) {
        float qv = q[n];
#pragma unroll
        for (int s = 0; s < TT; ++s) part[s] += qv * kt[((size_t)b * TT + s) * NN + n];
    }
    __shared__ float red[TT][4];
    __shared__ float sc[TT];
    int lane = threadIdx.x & 63, wid = threadIdx.x >> 6;
#pragma unroll
    for (int s = 0; s < TT; ++s) {
        float v = part[s];
#pragma unroll
        for (int m = 32; m >= 1; m >>= 1) v += __shfl_xor(v, m);
        if (lane == 0) red[s][wid] = v;
    }
    __syncthreads();
    if (threadIdx.x < TT)
        sc[threadIdx.x] = (red[threadIdx.x][0] + red[threadIdx.x][1] + red[threadIdx.x][2] +
                           red[threadIdx.x][3]) * 0.02209708691207961f;  // 1/sqrt(2048)
    __syncthreads();
    if (threadIdx.x == 0) {
        float m = sc[0];
#pragma unroll
        for (int s = 1; s < TT; ++s) m = fmaxf(m, sc[s]);
        float e[TT], sum = 0.f;
#pragma unroll
        for (int s = 0; s < TT; ++s) { e[s] = __expf(sc[s] - m); sum += e[s]; }
        float inv = 1.f / sum;
#pragma unroll
        for (int s = 0; s < TT; ++s) ta[((size_t)b * TT + t) * TT + s] = e[s] * inv;
    }
}

// ---------------------------------------------------------------------------
// K3 (per chunk): x_ta -> xT_c[bl][t*32+f][n] (bf16); qs/ks (global b) fused.
// ---------------------------------------------------------------------------
__global__ __launch_bounds__(256) void k_xta(
    const void* __restrict__ x, const float* __restrict__ ta,
    const void* __restrict__ wqs, const void* __restrict__ wks, const int* __restrict__ flag,
    __hip_bfloat16* __restrict__ xT, float* __restrict__ qs, float* __restrict__ ks, int b0) {
    int mf = flag[0];
    int gid = blockIdx.x * 256 + threadIdx.x;
    int fg = gid & 3;
    int n = (gid >> 2) & (NN - 1);
    int bl = gid >> 13;          // 0..chk-1 (block-uniform)
    int b = b0 + bl;
    __shared__ float sta[TT * TT];
    __shared__ float swq[32], swk[32];
    if (threadIdx.x < 144) sta[threadIdx.x] = ta[(size_t)b * 144 + threadIdx.x];
    else if (threadIdx.x >= 160 && threadIdx.x < 192) swq[threadIdx.x - 160] = ldf(wqs, threadIdx.x - 160, mf);
    else if (threadIdx.x >= 192 && threadIdx.x < 224) swk[threadIdx.x - 192] = ldf(wks, threadIdx.x - 192, mf);
    __syncthreads();

    float acc[TT][8];
#pragma unroll
    for (int t = 0; t < TT; ++t)
#pragma unroll
        for (int j = 0; j < 8; ++j) acc[t][j] = 0.f;

    for (int s = 0; s < TT; ++s) {
        float xv[8];
        load8d(x, (((size_t)(b * TT + s) * NN) + n) * FIN + fg * 8, mf, xv);
#pragma unroll
        for (int t = 0; t < TT; ++t) {
            float w = sta[t * TT + s];
#pragma unroll
            for (int j = 0; j < 8; ++j) acc[t][j] += w * xv[j];
        }
    }
    size_t xbase = (size_t)bl * 384 * NN;
#pragma unroll
    for (int t = 0; t < TT; ++t)
#pragma unroll
        for (int j = 0; j < 8; ++j)
            xT[xbase + (size_t)(t * 32 + fg * 8 + j) * NN + n] = __float2bfloat16(acc[t][j]);
#pragma unroll
    for (int t = 0; t < TT; ++t) {
        float pq = 0.f, pk = 0.f;
#pragma unroll
        for (int j = 0; j < 8; ++j) {
            pq += acc[t][j] * swq[fg * 8 + j];
            pk += acc[t][j] * swk[fg * 8 + j];
        }
        pq += __shfl_xor(pq, 1); pq += __shfl_xor(pq, 2);
        pk += __shfl_xor(pk, 1); pk += __shfl_xor(pk, 2);
        if (fg == 0) {
            qs[((size_t)b * NN + n) * TT + t] = pq;
            ks[((size_t)b * NN + n) * TT + t] = pk;
        }
    }
}

// ---------------------------------------------------------------------------
// K5 (per chunk): sa_c[bl][i][j] (bf16), softmax over j. 8 i-rows / block.
// ---------------------------------------------------------------------------
__global__ __launch_bounds__(256) void k_sattn(
    const float* __restrict__ qs, const float* __restrict__ ks,
    __hip_bfloat16* __restrict__ sa, int b0) {
    int bl = blockIdx.x >> 8;
    int b = b0 + bl;
    int i0 = (blockIdx.x & 255) * 8;
    __shared__ float qrow[8][TT];
    __shared__ float rbuf[4];
    if (threadIdx.x < 96) qrow[threadIdx.x / TT][threadIdx.x % TT] =
        qs[((size_t)b * NN + i0) * TT + threadIdx.x];
    __syncthreads();
    const float scale = 0.28867513459481287f;  // 1/sqrt(12)
    float sc[8][8];
#pragma unroll
    for (int c = 0; c < 8; ++c) {
        int j = threadIdx.x + (c << 8);
        const float* kr = ks + ((size_t)b * NN + j) * TT;
        float kv[TT];
        *(float4*)&kv[0] = *(const float4*)&kr[0];
        *(float4*)&kv[4] = *(const float4*)&kr[4];
        *(float4*)&kv[8] = *(const float4*)&kr[8];
#pragma unroll
        for (int r = 0; r < 8; ++r) {
            float d = 0.f;
#pragma unroll
            for (int t = 0; t < TT; ++t) d += qrow[r][t] * kv[t];
            sc[r][c] = d * scale;
        }
    }
    int lane = threadIdx.x & 63, wid = threadIdx.x >> 6;
#pragma unroll
    for (int r = 0; r < 8; ++r) {
        float v = -1e30f;
#pragma unroll
        for (int c = 0; c < 8; ++c) v = fmaxf(v, sc[r][c]);
#pragma unroll
        for (int m = 32; m >= 1; m >>= 1) v = fmaxf(v, __shfl_xor(v, m));
        if (lane == 0) rbuf[wid] = v;
        __syncthreads();
        float bmax = fmaxf(fmaxf(rbuf[0], rbuf[1]), fmaxf(rbuf[2], rbuf[3]));
        __syncthreads();
        float lsum = 0.f;
#pragma unroll
        for (int c = 0; c < 8; ++c) { float e = __expf(sc[r][c] - bmax); sc[r][c] = e; lsum += e; }
        v = lsum;
#pragma unroll
        for (int m = 32; m >= 1; m >>= 1) v += __shfl_xor(v, m);
        if (lane == 0) rbuf[wid] = v;
        __syncthreads();
        float inv = 1.f / (rbuf[0] + rbuf[1] + rbuf[2] + rbuf[3]);
        __syncthreads();
        size_t base = ((size_t)bl * NN + i0 + r) * NN + threadIdx.x;
#pragma unroll
        for (int c = 0; c < 8; ++c) sa[base + (c << 8)] = __float2bfloat16(sc[r][c] * inv);
    }
}

// ---------------------------------------------------------------------------
// K6 (per chunk): per (bl,kk):  C = (chebBF_k .* sa_bl) @ X_bl -> rhs_c
//   M=2048(i), N=384(all tf), K=2048(j).
//   r8: B VIA global_load_lds. r2-r7 pipe accounting: MFMA 22 / VALU 18 /
//   LDS 15 / TA ~22% — transaction-issue co-bound, pipes not overlapping.
//   B was read per-WAVE from global (4x duplicate) as 16-line split loads.
//   Now B staged ONCE per block per K-step by contiguous 1KB gload_lds DMA
//   (no VGPR round-trip). 16B-chunk XOR swizzle (chunk cc of row r holds
//   global chunk cc^(r&3)) applied on the SOURCE address (linear LDS dest,
//   rule #21) -> b-frag ds_read_b128 is ~4-way instead of 16-way.
//   A-path unchanged (register staging, proven). kk fastest in grid so the
//   3 kk-blocks sharing sa/xT slices are co-resident (L2 reuse).
//   LDS 58KB -> 2 blocks/CU. Stage issued AFTER barrier+frag-reads so the
//   barrier's vmcnt(0) drain only sees loads issued a full MFMA block ago.
// ---------------------------------------------------------------------------
__global__ __launch_bounds__(256, 2) void k_gemm_cheb(
    const __hip_bfloat16* __restrict__ chebBF, const __hip_bfloat16* __restrict__ sa,
    const __hip_bfloat16* __restrict__ xT, __hip_bfloat16* __restrict__ rhs) {
    int it = blockIdx.x / 3, kk = blockIdx.x % 3;   // kk fastest
    int bl = blockIdx.y;

    __shared__ __hip_bfloat16 As[2][64][40];        // 10.0 KB
    __shared__ __hip_bfloat16 Bs[2][384 * 32];      // 48.0 KB; row c at c*32

    int tid = threadIdx.x;
    int wid = tid >> 6, lane = tid & 63;
    int wn = wid * 96;
    int lr = lane & 15, kq = (lane >> 4) * 8;

    const size_t i0 = (size_t)it * 64;
    const __hip_bfloat16* chebK = chebBF + (size_t)kk * NN * NN;
    const __hip_bfloat16* saB = sa + (size_t)bl * NN * NN;
    const __hip_bfloat16* xTB = xT + (size_t)bl * 384 * NN;

    int srow = tid >> 2;          // 0..63
    int scol = (tid & 3) * 8;     // 0,8,16,24
    const __hip_bfloat16* cptr = &chebK[(i0 + srow) * NN + scol];
    const __hip_bfloat16* sptr = &saB[(i0 + srow) * NN + scol];

    // B staging: wave w stages rows [wn, wn+96), 6 gload16/step, 16 rows each.
    // lane: row r = wn + v*16 + (lane>>2); global chunk g = (lane&3)^(r&3);
    // (r&3) == ((lane>>2)&3) since wn+v*16 is a multiple of 4.
    int brow = wn + (lane >> 2);
    int gck = ((lane & 3) ^ ((lane >> 2) & 3)) * 8;
    const __hip_bfloat16* bsrc = &xTB[(size_t)brow * NN + gck];

    vf32x4 acc[4][6];
    vf32x4 z4 = {0.f, 0.f, 0.f, 0.f};
#pragma unroll
    for (int mi = 0; mi < 4; ++mi)
#pragma unroll
        for (int ni = 0; ni < 6; ++ni) acc[mi][ni] = z4;

    // prologue: step-0 A regs + step-0 B stage
    uint4 cu = *reinterpret_cast<const uint4*>(cptr);
    uint4 su = *reinterpret_cast<const uint4*>(sptr);
#pragma unroll
    for (int v = 0; v < 6; ++v)
        gload16(bsrc + (size_t)(v * 16) * NN, &Bs[0][(wn + v * 16) * 32]);

    for (int step = 0; step < 64; ++step) {
        int p = step & 1;
        // A-product (regs from prev iter) -> LDS
        {
            uint4 pv = mulpack8u(cu, su);
            *reinterpret_cast<uint4*>(&As[p][srow][scol]) = pv;
        }
        __syncthreads();   // drains prev-step gloads + A-loads (≥1 MFMA block old)

        // fragments from LDS
        vbf16x8 a[4];
#pragma unroll
        for (int mi = 0; mi < 4; ++mi)
            a[mi] = *reinterpret_cast<const vbf16x8*>(&As[p][mi * 16 + lr][kq]);
        vbf16x8 b[6];
#pragma unroll
        for (int ni = 0; ni < 6; ++ni) {
            int r = wn + ni * 16 + lr;
            int pos = ((kq >> 3) ^ (r & 3)) * 8;   // un-swizzle chunk
            b[ni] = *reinterpret_cast<const vbf16x8*>(&Bs[p][r * 32 + pos]);
        }

        // issue next-step loads (in flight across the MFMA block; tail clamp)
        int k0n = (step < 63) ? (step + 1) * 32 : step * 32;
        cu = *reinterpret_cast<const uint4*>(cptr + k0n);
        su = *reinterpret_cast<const uint4*>(sptr + k0n);
#pragma unroll
        for (int v = 0; v < 6; ++v)
            gload16(bsrc + (size_t)(v * 16) * NN + k0n, &Bs[p ^ 1][(wn + v * 16) * 32]);

#pragma unroll
        for (int ni = 0; ni < 6; ++ni)
#pragma unroll
            for (int mi = 0; mi < 4; ++mi)
                acc[mi][ni] = __builtin_amdgcn_mfma_f32_16x16x32_bf16(a[mi], b[ni], acc[mi][ni], 0, 0, 0);
        // Bs[p^1]/As[p] rewritten only after the next barrier has drained
        // this step's reads — single barrier per step is safe.
    }

    // epilogue: row = mi*16 + quad*4 + g; col = wn + ni*16 + lr
#pragma unroll
    for (int mi = 0; mi < 4; ++mi)
#pragma unroll
        for (int ni = 0; ni < 6; ++ni)
#pragma unroll
            for (int g = 0; g < 4; ++g) {
                int row = mi * 16 + ((lane >> 4) << 2) + g;
                int col = wn + ni * 16 + lr;
                size_t i = i0 + row;
                int t = col >> 5, f = col & 31;
                rhs[(((size_t)bl * NN + i) * TT + t) * 96 + kk * 32 + f] =
                    __float2bfloat16(acc[mi][ni][g]);
            }
}

// ---------------------------------------------------------------------------
// K7a (per chunk): G = relu(rhs @ Theta)  rows (bl,n,t), K=96, N=64
//      G stored [bl][t][n][o] bf16
// ---------------------------------------------------------------------------
__global__ __launch_bounds__(256) void k_theta(
    const __hip_bfloat16* __restrict__ rhs, const __hip_bfloat16* __restrict__ Tt,
    __hip_bfloat16* __restrict__ G) {
    __shared__ __hip_bfloat16 Ts[64][104];
    int tid = threadIdx.x;
    int srow = tid >> 2, scol = (tid & 3) * 8;
#pragma unroll
    for (int c0 = 0; c0 < 96; c0 += 32)
        *reinterpret_cast<uint4*>(&Ts[srow][c0 + scol]) =
            *reinterpret_cast<const uint4*>(&Tt[(size_t)srow * 96 + c0 + scol]);
    __syncthreads();
    int wid = tid >> 6, lane = tid & 63;
    int lr = lane & 15, kq = (lane >> 4) * 8;
    size_t r0 = (size_t)blockIdx.x * 128 + wid * 32;
    vf32x4 acc[2][4];
    vf32x4 z4 = {0.f, 0.f, 0.f, 0.f};
#pragma unroll
    for (int mi = 0; mi < 2; ++mi)
#pragma unroll
        for (int ni = 0; ni < 4; ++ni) acc[mi][ni] = z4;
#pragma unroll
    for (int s = 0; s < 3; ++s) {
        vbf16x8 a[2], bf[4];
#pragma unroll
        for (int mi = 0; mi < 2; ++mi)
            a[mi] = *reinterpret_cast<const vbf16x8*>(&rhs[(r0 + mi * 16 + lr) * 96 + s * 32 + kq]);
#pragma unroll
        for (int ni = 0; ni < 4; ++ni)
            bf[ni] = *reinterpret_cast<const vbf16x8*>(&Ts[ni * 16 + lr][s * 32 + kq]);
#pragma unroll
        for (int mi = 0; mi < 2; ++mi)
#pragma unroll
            for (int ni = 0; ni < 4; ++ni)
                acc[mi][ni] = __builtin_amdgcn_mfma_f32_16x16x32_bf16(a[mi], bf[ni], acc[mi][ni], 0, 0, 0);
    }
#pragma unroll
    for (int mi = 0; mi < 2; ++mi)
#pragma unroll
        for (int ni = 0; ni < 4; ++ni)
#pragma unroll
            for (int g = 0; g < 4; ++g) {
                size_t r = r0 + mi * 16 + ((lane >> 4) << 2) + g;  // (bl*N+n)*T+t
                int col = ni * 16 + (lane & 15);
                int t = (int)(r % TT);
                size_t bn = r / TT;
                int n = (int)(bn & (NN - 1));
                int bl = (int)(bn >> 11);
                float v = fmaxf(acc[mi][ni][g], 0.f);
                G[(((size_t)bl * TT + t) * NN + n) * 64 + col] = __float2bfloat16(v);
            }
}

// ---------------------------------------------------------------------------
// K7b (per chunk): y = relu([G(t-1),G(t),G(t+1),x] @ Wcat + bias); LayerNorm
//      block = (nblk, t, bl); 128 rows (n), K=224, N=64
// ---------------------------------------------------------------------------
__global__ __launch_bounds__(256) void k_final(
    const __hip_bfloat16* __restrict__ G, const void* __restrict__ x,
    const __hip_bfloat16* __restrict__ Wt, const float* __restrict__ biasC,
    const void* __restrict__ ln_g, const void* __restrict__ ln_b,
    const int* __restrict__ flag, void* __restrict__ outv, int b0) {
    int mf = flag[0];
    int n0 = blockIdx.x * 128;
    int t = blockIdx.y;
    int bl = blockIdx.z;
    int b = b0 + bl;
    __shared__ __hip_bfloat16 Ws[64][232];
    __shared__ float sg[64], sb[64], sbias[64];
    int tid = threadIdx.x;
    int srow = tid >> 2, scol = (tid & 3) * 8;
#pragma unroll
    for (int c0 = 0; c0 < 224; c0 += 32)
        *reinterpret_cast<uint4*>(&Ws[srow][c0 + scol]) =
            *reinterpret_cast<const uint4*>(&Wt[(size_t)srow * 224 + c0 + scol]);
    if (tid < 64) {
        sg[tid] = ldf(ln_g, tid, mf);
        sb[tid] = ldf(ln_b, tid, mf);
        sbias[tid] = biasC[tid];
    }
    __syncthreads();
    int wid = tid >> 6, lane = tid & 63;
    int lr = lane & 15, kq = (lane >> 4) * 8;
    int rw = n0 + wid * 32;
    vf32x4 acc[2][4];
    vf32x4 z4 = {0.f, 0.f, 0.f, 0.f};
#pragma unroll
    for (int mi = 0; mi < 2; ++mi)
#pragma unroll
        for (int ni = 0; ni < 4; ++ni) acc[mi][ni] = z4;

    vbf16x8 zfrag = {0, 0, 0, 0, 0, 0, 0, 0};
#pragma unroll
    for (int s = 0; s < 7; ++s) {
        int kb = s * 32;
        vbf16x8 a[2], bf[4];
#pragma unroll
        for (int ni = 0; ni < 4; ++ni)
            bf[ni] = *reinterpret_cast<const vbf16x8*>(&Ws[ni * 16 + lr][kb + kq]);
        if (s < 6) {
            int dt = s >> 1;
            int t2 = t + dt - 1;
            int off = (s & 1) * 32 + kq;
            if (t2 >= 0 && t2 < TT) {
#pragma unroll
                for (int mi = 0; mi < 2; ++mi)
                    a[mi] = *reinterpret_cast<const vbf16x8*>(
                        &G[(((size_t)bl * TT + t2) * NN + rw + mi * 16 + lr) * 64 + off]);
            } else {
                a[0] = zfrag; a[1] = zfrag;
            }
        } else {
#pragma unroll
            for (int mi = 0; mi < 2; ++mi) {
                float xv[8];
                load8d(x, (((size_t)b * TT + t) * NN + rw + mi * 16 + lr) * FIN + kq, mf, xv);
                a[mi] = pack8(xv);
            }
        }
#pragma unroll
        for (int mi = 0; mi < 2; ++mi)
#pragma unroll
            for (int ni = 0; ni < 4; ++ni)
                acc[mi][ni] = __builtin_amdgcn_mfma_f32_16x16x32_bf16(a[mi], bf[ni], acc[mi][ni], 0, 0, 0);
    }
    float vals[2][4][4];
#pragma unroll
    for (int mi = 0; mi < 2; ++mi)
#pragma unroll
        for (int ni = 0; ni < 4; ++ni) {
            int col = ni * 16 + lr;
#pragma unroll
            for (int g = 0; g < 4; ++g)
                vals[mi][ni][g] = fmaxf(acc[mi][ni][g] + sbias[col], 0.f);
        }
#pragma unroll
    for (int mi = 0; mi < 2; ++mi)
#pragma unroll
        for (int g = 0; g < 4; ++g) {
            float s1 = 0.f, s2 = 0.f;
#pragma unroll
            for (int ni = 0; ni < 4; ++ni) { float v = vals[mi][ni][g]; s1 += v; s2 += v * v; }
            s1 += __shfl_xor(s1, 1); s2 += __shfl_xor(s2, 1);
            s1 += __shfl_xor(s1, 2); s2 += __shfl_xor(s2, 2);
            s1 += __shfl_xor(s1, 4); s2 += __shfl_xor(s2, 4);
            s1 += __shfl_xor(s1, 8); s2 += __shfl_xor(s2, 8);
            float mean = s1 * (1.f / 64.f);
            float var = fmaxf(s2 * (1.f / 64.f) - mean * mean, 0.f);
            float rstd = rsqrtf(var + 1e-5f);
            int row = wid * 32 + mi * 16 + ((lane >> 4) << 2) + g;
#pragma unroll
            for (int ni = 0; ni < 4; ++ni) {
                int col = ni * 16 + lr;
                float y = (vals[mi][ni][g] - mean) * rstd * sg[col] + sb[col];
                size_t oi = (((size_t)b * TT + t) * NN + n0 + row) * 64 + col;
                if (mf) ((float*)outv)[oi] = y;
                else ((__hip_bfloat16*)outv)[oi] = __float2bfloat16(y);
            }
        }
}

// ---------------------------------------------------------------------------
extern "C" void kernel_launch(void* const* d_in, const int* in_sizes, int n_in,
                              void* d_out, int out_size, void* d_ws, size_t ws_size,
                              hipStream_t stream) {
    const void* x      = d_in[0];
    const void* cheb   = d_in[1];
    const void* wq_t   = d_in[2];
    const void* wk_t   = d_in[3];
    const void* wq_s   = d_in[4];
    const void* wk_s   = d_in[5];
    const void* theta  = d_in[6];
    const void* tconvw = d_in[7];
    const void* tconvb = d_in[8];
    const void* rconvw = d_in[9];
    const void* rconvb = d_in[10];
    const void* ln_g   = d_in[11];
    const void* ln_b   = d_in[12];

    // fixed-region sizes
    const size_t sflag = 256;
    const size_t sqt   = (size_t)BB * TT * NN * 4;   // 1.5 MB (also hosts qs/ks)
    const size_t sta   = 16384;
    const size_t sTt   = 64 * 96 * 2;
    const size_t sWt   = 64 * 224 * 2;
    const size_t sbias = 256;
    const size_t scheb = (size_t)KCH * NN * NN * 2;  // 25.2 MB bf16 cheb
    const size_t fixed = sflag + 2 * sqt + sta + sTt + sWt + sbias + scheb;
    // per-chunk-batch sizes
    const size_t pxT  = (size_t)384 * NN * 2;          // 1.5 MiB
    const size_t psa  = (size_t)NN * NN * 2;           // 8.0 MiB (hosts G too: 3 MiB)
    const size_t prhs = (size_t)NN * TT * 96 * 2;      // 4.5 MiB
    const size_t perb = pxT + psa + prhs;

    int chk = 0;
    for (int c = 16; c >= 1; c >>= 1)
        if (fixed + (size_t)c * perb <= ws_size) { chk = c; break; }

    if (chk == 0) {
        k_emergency<<<(out_size + 255) / 256, 256, 0, stream>>>(
            (__hip_bfloat16*)d_out, (size_t)out_size);
        return;
    }

    char* ws = (char*)d_ws;
    size_t off = 0;
    int*   flag = (int*)(ws + off);             off += sflag;
    float* qt   = (float*)(ws + off);           off += sqt;
    float* kt   = (float*)(ws + off);           off += sqt;
    float* ta   = (float*)(ws + off);           off += sta;
    __hip_bfloat16* Tt = (__hip_bfloat16*)(ws + off);  off += sTt;
    __hip_bfloat16* Wt = (__hip_bfloat16*)(ws + off);  off += sWt;
    float* biasC = (float*)(ws + off);          off += sbias;
    __hip_bfloat16* chebBF = (__hip_bfloat16*)(ws + off); off += scheb;
    __hip_bfloat16* xTc  = (__hip_bfloat16*)(ws + off); off += (size_t)chk * pxT;
    __hip_bfloat16* saC  = (__hip_bfloat16*)(ws + off); off += (size_t)chk * psa;
    __hip_bfloat16* rhsC = (__hip_bfloat16*)(ws + off); off += (size_t)chk * prhs;
    // aliases (lifetimes disjoint):
    float* qs = qt;                 // qt/kt dead after k_tattn
    float* ks = kt;
    __hip_bfloat16* Gc = saC;       // sa dead after k_gemm_cheb; G (chk*3MiB) fits

    k_detect<<<1, 256, 0, stream>>>(x, flag);
    k_cvt_cheb<<<(KCH * NN * NN) / 2048, 256, 0, stream>>>(cheb, flag, chebBF);
    k_prep<<<56, 256, 0, stream>>>(theta, tconvw, tconvb, rconvw, rconvb, flag, Tt, Wt, biasC);
    k_qtkt<<<(BB * TT * NN) / 256, 256, 0, stream>>>(x, wq_t, wk_t, flag, qt, kt);
    k_tattn<<<BB * TT, 256, 0, stream>>>(qt, kt, ta);
    for (int b0 = 0; b0 < BB; b0 += chk) {
        k_xta<<<(chk * NN * 4) / 256, 256, 0, stream>>>(x, ta, wq_s, wk_s, flag, xTc, qs, ks, b0);
        k_sattn<<<chk * (NN / 8), 256, 0, stream>>>(qs, ks, saC, b0);
        k_gemm_cheb<<<dim3(96, chk), 256, 0, stream>>>(chebBF, saC, xTc, rhsC);
        k_theta<<<(chk * NN * TT) / 128, 256, 0, stream>>>(rhsC, Tt, Gc);
        k_final<<<dim3(NN / 128, TT, chk), 256, 0, stream>>>(Gc, x, Wt, biasC, ln_g, ln_b, flag, d_out, b0);
    }
}